// Round 7
// baseline (2378.057 us; speedup 1.0000x reference)
//
#include <hip/hip_runtime.h>
#include <hip/hip_bf16.h>
#include <math.h>

// Problem dims (fixed)
#define T_STEPS 512
#define IN_DIM  1024
#define H_DIM   2048
#define Y_DIM   1024

// K2 geometry: 128 blocks x 512 threads (8 waves). Block owns 16 columns,
// wave w owns columns j0 = 16*blockIdx + 2w, j0+1. Weights in VGPRs.
// 82 KB LDS forces 1 block/CU (exclusive SIMDs for the critical path).
#define NBLK2 128
#define BT2   512
#define NWORD (H_DIM / 2)     // 1024 packed transit words per step

// ---------- helpers ----------
static __device__ __forceinline__ unsigned f2bf(float f) {
    unsigned u = __float_as_uint(f);
    return ((u + 0x7FFFu + ((u >> 16) & 1u)) >> 16) & 0xFFFFu;   // RNE
}
static __device__ __forceinline__ float bflo(unsigned p) { return __uint_as_float(p << 16); }
static __device__ __forceinline__ float bfhi(unsigned p) { return __uint_as_float(p & 0xFFFF0000u); }

// ---------- K1 / K3: tiled fp32 GEMM, C[M,N] = A[M,K] @ B[K,N] + bias[N] ----------
#define TM 64
#define TN 128
#define TK 16

__global__ __launch_bounds__(256) void gemm_bias(
    const float* __restrict__ A, const float* __restrict__ B,
    const float* __restrict__ bias, float* __restrict__ C,
    int M, int N, int K, int lda, int ldb, int ldc)
{
    __shared__ float As[TK][TM + 4];
    __shared__ float Bs[TK][TN + 4];

    const int n0 = blockIdx.x * TN;
    const int m0 = blockIdx.y * TM;
    const int tid = threadIdx.x;
    const int tx = tid & 15;        // N: 8 floats each
    const int ty = tid >> 4;        // M: 4 rows each

    float acc[4][8] = {};

    for (int k0 = 0; k0 < K; k0 += TK) {
        {
            int mm = tid & 63, kq = tid >> 6;
            float4 a = *(const float4*)&A[(m0 + mm) * lda + k0 + 4 * kq];
            As[4 * kq + 0][mm] = a.x;
            As[4 * kq + 1][mm] = a.y;
            As[4 * kq + 2][mm] = a.z;
            As[4 * kq + 3][mm] = a.w;
        }
        #pragma unroll
        for (int l = tid; l < 512; l += 256) {
            int kk = l >> 5, jj = (l & 31) * 4;
            *(float4*)&Bs[kk][jj] = *(const float4*)&B[(k0 + kk) * ldb + n0 + jj];
        }
        __syncthreads();
        #pragma unroll
        for (int kk = 0; kk < TK; ++kk) {
            float4 a  = *(const float4*)&As[kk][ty * 4];
            float4 b0 = *(const float4*)&Bs[kk][tx * 8];
            float4 b1 = *(const float4*)&Bs[kk][tx * 8 + 4];
            const float av[4] = {a.x, a.y, a.z, a.w};
            const float bv[8] = {b0.x, b0.y, b0.z, b0.w, b1.x, b1.y, b1.z, b1.w};
            #pragma unroll
            for (int r = 0; r < 4; ++r)
                #pragma unroll
                for (int c = 0; c < 8; ++c)
                    acc[r][c] = fmaf(av[r], bv[c], acc[r][c]);
        }
        __syncthreads();
    }

    float4 bv0 = *(const float4*)&bias[n0 + tx * 8];
    float4 bv1 = *(const float4*)&bias[n0 + tx * 8 + 4];
    const float bb[8] = {bv0.x, bv0.y, bv0.z, bv0.w, bv1.x, bv1.y, bv1.z, bv1.w};
    #pragma unroll
    for (int r = 0; r < 4; ++r) {
        float4 o0, o1;
        o0.x = acc[r][0] + bb[0]; o0.y = acc[r][1] + bb[1];
        o0.z = acc[r][2] + bb[2]; o0.w = acc[r][3] + bb[3];
        o1.x = acc[r][4] + bb[4]; o1.y = acc[r][5] + bb[5];
        o1.z = acc[r][6] + bb[6]; o1.w = acc[r][7] + bb[7];
        float* cp = &C[(m0 + ty * 4 + r) * ldc + n0 + tx * 8];
        *(float4*)cp = o0;
        *(float4*)(cp + 4) = o1;
    }
}

// ---------- K2: barrier-free dataflow recurrence ----------
// vs R6: (1) recurrent weights live in 64 VGPRs/lane (LDS holds ONLY h ->
// compute phase is 8x ds_read_b128/wave, conflict-free); (2) h transit is
// bf16-packed: one 8B word = {epoch u32, bf16 h[2g], bf16 h[2g+1]} stored
// with a single relaxed agent-scope atomic -> 1024 words/step, 2 words/thread
// acquire; (3) 128 blocks (smaller straggler pool), 1 publish store/wave.
// Gate blend keeps full-f32 carried state; only matmul-input h is bf16.
__global__ __launch_bounds__(BT2) void gru_seq(
    const float* __restrict__ Wu_h,   // = Wu + IN_DIM*H_DIM  (h-part rows)
    const float* __restrict__ Wc_h,
    const float* __restrict__ XU,     // [T,H]  x@Wu_x + bu
    const float* __restrict__ XC,     // [T,H]  x@Wc_x + bc
    const float* __restrict__ h0,     // [H]
    unsigned long long* __restrict__ Hp,  // [T,NWORD] packed transit words
    float* __restrict__ H)                // [T,H] plain f32 (for K3)
{
    // 2 x 10496 floats = 82 KB: only [0..2047] used per buffer; size forces
    // exactly 1 block/CU so the block owns all 4 SIMDs.
    __shared__ float hbuf[2][10496];

    const int tid  = threadIdx.x;
    const int w    = tid >> 6;
    const int lane = tid & 63;
    const int jb   = blockIdx.x * 16;
    const int j0   = jb + 2 * w;

    // ---- one-time weight staging into 64 VGPRs ----
    // Layout matches b128 h reads: iteration q reads h elements e..e+3 where
    // e = 4*(q*64+lane). wrX[2q] covers (e,e+1), wrX[2q+1] covers (e+2,e+3).
    unsigned wru0[16], wru1[16], wrc0[16], wrc1[16];
    #pragma unroll
    for (int q = 0; q < 8; ++q) {
        int e = 4 * (q * 64 + lane);
        const float* u = Wu_h + (size_t)e * H_DIM + j0;
        const float* c = Wc_h + (size_t)e * H_DIM + j0;
        wru0[2*q]   = f2bf(u[0])              | (f2bf(u[(size_t)H_DIM])     << 16);
        wru0[2*q+1] = f2bf(u[2*(size_t)H_DIM]) | (f2bf(u[3*(size_t)H_DIM])  << 16);
        wru1[2*q]   = f2bf(u[1])              | (f2bf(u[(size_t)H_DIM+1])   << 16);
        wru1[2*q+1] = f2bf(u[2*(size_t)H_DIM+1]) | (f2bf(u[3*(size_t)H_DIM+1]) << 16);
        wrc0[2*q]   = f2bf(c[0])              | (f2bf(c[(size_t)H_DIM])     << 16);
        wrc0[2*q+1] = f2bf(c[2*(size_t)H_DIM]) | (f2bf(c[3*(size_t)H_DIM])  << 16);
        wrc1[2*q]   = f2bf(c[1])              | (f2bf(c[(size_t)H_DIM+1])   << 16);
        wrc1[2*q+1] = f2bf(c[2*(size_t)H_DIM+1]) | (f2bf(c[3*(size_t)H_DIM+1]) << 16);
    }

    // carried f32 h for this wave's own columns (lane0's copy is authoritative)
    float hc0 = h0[j0], hc1 = h0[j0 + 1];
    const int myword = blockIdx.x * 8 + w;     // published word index

    for (int t = 0; t < T_STEPS; ++t) {
        // x-contributions (normal cached loads, issued before the spin)
        float2 xu = make_float2(0.f, 0.f), xc = make_float2(0.f, 0.f);
        if (lane == 0) {
            xu = *(const float2*)(XU + (size_t)t * H_DIM + j0);
            xc = *(const float2*)(XC + (size_t)t * H_DIM + j0);
        }

        float* hb = hbuf[t & 1];

        // ---- acquire h[t-1]: 2 packed words per thread, throttled retry ----
        if (t == 0) {
            *(float4*)&hb[4 * tid] = *(const float4*)&h0[4 * tid];
        } else {
            const unsigned long long* src = Hp + (size_t)(t - 1) * NWORD;
            unsigned long long p0 =
                __hip_atomic_load(src + 2 * tid,     __ATOMIC_RELAXED, __HIP_MEMORY_SCOPE_AGENT);
            unsigned long long p1 =
                __hip_atomic_load(src + 2 * tid + 1, __ATOMIC_RELAXED, __HIP_MEMORY_SCOPE_AGENT);
            const unsigned tag = (unsigned)t;
            int s0 = (unsigned)(p0 >> 32) != tag;
            int s1 = (unsigned)(p1 >> 32) != tag;
            while (__any(s0 | s1)) {
                __builtin_amdgcn_s_sleep(1);
                if (s0) {
                    p0 = __hip_atomic_load(src + 2 * tid, __ATOMIC_RELAXED, __HIP_MEMORY_SCOPE_AGENT);
                    s0 = (unsigned)(p0 >> 32) != tag;
                }
                if (s1) {
                    p1 = __hip_atomic_load(src + 2 * tid + 1, __ATOMIC_RELAXED, __HIP_MEMORY_SCOPE_AGENT);
                    s1 = (unsigned)(p1 >> 32) != tag;
                }
            }
            float4 hv;
            hv.x = bflo((unsigned)p0);
            hv.y = bfhi((unsigned)p0);
            hv.z = bflo((unsigned)p1);
            hv.w = bfhi((unsigned)p1);
            *(float4*)&hb[4 * tid] = hv;
        }
        __syncthreads();   // h[t-1] fully in LDS

        // ---- 4 dot products: 8x ds_read_b128 + 16 FMA per iteration ----
        float au0 = 0.f, au1 = 0.f, ac0 = 0.f, ac1 = 0.f;
        #pragma unroll
        for (int q = 0; q < 8; ++q) {
            float4 h4 = *(const float4*)&hb[4 * (q * 64 + lane)];
            unsigned a, b;
            a = wru0[2*q]; b = wru0[2*q+1];
            au0 = fmaf(h4.x, bflo(a), au0); au0 = fmaf(h4.y, bfhi(a), au0);
            au0 = fmaf(h4.z, bflo(b), au0); au0 = fmaf(h4.w, bfhi(b), au0);
            a = wru1[2*q]; b = wru1[2*q+1];
            au1 = fmaf(h4.x, bflo(a), au1); au1 = fmaf(h4.y, bfhi(a), au1);
            au1 = fmaf(h4.z, bflo(b), au1); au1 = fmaf(h4.w, bfhi(b), au1);
            a = wrc0[2*q]; b = wrc0[2*q+1];
            ac0 = fmaf(h4.x, bflo(a), ac0); ac0 = fmaf(h4.y, bfhi(a), ac0);
            ac0 = fmaf(h4.z, bflo(b), ac0); ac0 = fmaf(h4.w, bfhi(b), ac0);
            a = wrc1[2*q]; b = wrc1[2*q+1];
            ac1 = fmaf(h4.x, bflo(a), ac1); ac1 = fmaf(h4.y, bfhi(a), ac1);
            ac1 = fmaf(h4.z, bflo(b), ac1); ac1 = fmaf(h4.w, bfhi(b), ac1);
        }
        #pragma unroll
        for (int off = 32; off; off >>= 1) {
            au0 += __shfl_down(au0, off);
            au1 += __shfl_down(au1, off);
            ac0 += __shfl_down(ac0, off);
            ac1 += __shfl_down(ac1, off);
        }

        if (lane == 0) {
            float pu0 = au0 + xu.x, pu1 = au1 + xu.y;
            float pc0 = ac0 + xc.x, pc1 = ac1 + xc.y;
            // fast sigmoid (saturates correctly at both ends)
            float ug0 = 1.f / (1.f + __expf(-pu0));
            float ug1 = 1.f / (1.f + __expf(-pu1));
            // fast tanh, sign-safe: tanh(|x|) = (1-e)/(1+e), e = exp(-2|x|)
            float e0 = __expf(-2.f * fabsf(pc0));
            float e1 = __expf(-2.f * fabsf(pc1));
            float cg0 = copysignf((1.f - e0) / (1.f + e0), pc0);
            float cg1 = copysignf((1.f - e1) / (1.f + e1), pc1);
            float hn0 = ug0 * cg0 + (1.f - ug0) * hc0;
            float hn1 = ug1 * cg1 + (1.f - ug1) * hc1;
            hc0 = hn0; hc1 = hn1;

            // single tagged publish: epoch + both columns in one 8B word
            unsigned lo = f2bf(hn0) | (f2bf(hn1) << 16);
            __hip_atomic_store(Hp + (size_t)t * NWORD + myword,
                               ((unsigned long long)(unsigned)(t + 1) << 32) | lo,
                               __ATOMIC_RELAXED, __HIP_MEMORY_SCOPE_AGENT);
            // plain f32 copy for K3 (visible at kernel boundary)
            *(float2*)(H + (size_t)t * H_DIM + j0) = make_float2(hn0, hn1);
        }
        // no trailing barrier: double-buffered hbuf + acquire gating make it safe
        // (a wave can only reach step t+2's fill after ALL waves published t+1,
        //  which implies everyone is done reading hbuf[t&1])
    }
}

extern "C" void kernel_launch(void* const* d_in, const int* in_sizes, int n_in,
                              void* d_out, int out_size, void* d_ws, size_t ws_size,
                              hipStream_t stream)
{
    const float* x   = (const float*)d_in[0];   // [1,512,1024]
    const float* h0  = (const float*)d_in[1];   // [2048]
    const float* Wc  = (const float*)d_in[2];   // [3072,2048]
    const float* Wu  = (const float*)d_in[3];   // [3072,2048]
    const float* bc  = (const float*)d_in[4];   // [2048]
    const float* bu  = (const float*)d_in[5];   // [2048]
    const float* Why = (const float*)d_in[6];   // [2048,1024]
    const float* by  = (const float*)d_in[7];   // [1024]
    float* out = (float*)d_out;                 // ys[512*1024] then h_final[2048]

    float* ws = (float*)d_ws;
    float* XU = ws;                                        // 512*2048 f32
    float* XC = ws + (T_STEPS * H_DIM);                    // 512*2048 f32
    float* H  = ws + 2 * (T_STEPS * H_DIM);                // 512*2048 f32 (plain)
    unsigned long long* Hp =
        (unsigned long long*)(ws + 3 * (T_STEPS * H_DIM)); // 512*1024 x 8B transit

    // K1: XU = x @ Wu[0:1024,:] + bu ; XC = x @ Wc[0:1024,:] + bc
    gemm_bias<<<dim3(H_DIM / TN, T_STEPS / TM), 256, 0, stream>>>(
        x, Wu, bu, XU, T_STEPS, H_DIM, IN_DIM, IN_DIM, H_DIM, H_DIM);
    gemm_bias<<<dim3(H_DIM / TN, T_STEPS / TM), 256, 0, stream>>>(
        x, Wc, bc, XC, T_STEPS, H_DIM, IN_DIM, IN_DIM, H_DIM, H_DIM);

    // K2: barrier-free dataflow recurrence (Hp needs no init: 0xAA poison
    // can never equal a valid epoch 1..512)
    gru_seq<<<NBLK2, BT2, 0, stream>>>(
        Wu + IN_DIM * H_DIM, Wc + IN_DIM * H_DIM, XU, XC, h0, Hp, H);

    // K3: ys = H @ Why + by
    gemm_bias<<<dim3(Y_DIM / TN, T_STEPS / TM), 256, 0, stream>>>(
        H, Why, by, out, T_STEPS, Y_DIM, H_DIM, H_DIM, Y_DIM, Y_DIM);

    // h_final = H[511]
    hipMemcpyAsync(out + T_STEPS * Y_DIM, H + (T_STEPS - 1) * H_DIM,
                   H_DIM * sizeof(float), hipMemcpyDeviceToDevice, stream);
}